// Round 4
// baseline (404.148 us; speedup 1.0000x reference)
//
#include <hip/hip_runtime.h>
#include <math.h>

// HungarianLoss, fused single kernel. One block (256 threads = 4 waves) per
// batch element:
//   Phase A (4 waves): global_load_lds (16B) staging of all inputs into LDS
//                      (no VGPR round-trip -> no scratch spill).
//   Phase B (4 waves): -log_softmax in place in LDS.
//   Phase C (4 waves): per-row min/argmin (25 rows/wave) -> duals u, greedy
//                      column claims via LDS atomicMin.
//   Phase D (wave 0):  LAPJV augmenting-row-reduction (1 scan per free row,
//                      displacement chains) then JV shortest-augmenting-path
//                      Dijkstra for any leftovers. Register-resident
//                      v/ds/way/p and row data (readlane broadcasts).
//   Phase E (wave 0):  matched CE + L1 loss from LDS, DPP reduce, atomicAdd.

#define NQ  900    // queries (columns)
#define NQP 960    // padded to 15*64
#define NG  100    // gt boxes (rows)
#define NC  7
#define KS  15     // column slots per lane
#define INFF __builtin_inff()

__device__ __forceinline__ float readlane_f(float x, int l) {
  return __int_as_float(__builtin_amdgcn_readlane(__float_as_int(x), l));
}

template<int CTRL>
__device__ __forceinline__ float dpp_min_step(float x) {
  int y = __builtin_amdgcn_update_dpp(__float_as_int(x), __float_as_int(x),
                                      CTRL, 0xf, 0xf, false);
  return fminf(x, __int_as_float(y));
}
__device__ __forceinline__ float wave_min_b(float x) {
  x = dpp_min_step<0x111>(x);  // row_shr:1
  x = dpp_min_step<0x112>(x);  // row_shr:2
  x = dpp_min_step<0x114>(x);  // row_shr:4
  x = dpp_min_step<0x118>(x);  // row_shr:8
  x = dpp_min_step<0x142>(x);  // row_bcast:15
  x = dpp_min_step<0x143>(x);  // row_bcast:31
  return __int_as_float(__builtin_amdgcn_readlane(__float_as_int(x), 63));
}

template<int CTRL>
__device__ __forceinline__ float dpp_add_step(float x) {
  int y = __builtin_amdgcn_update_dpp(0, __float_as_int(x),
                                      CTRL, 0xf, 0xf, true);
  return x + __int_as_float(y);
}
__device__ __forceinline__ float wave_sum_b(float x) {
  x = dpp_add_step<0x111>(x);
  x = dpp_add_step<0x112>(x);
  x = dpp_add_step<0x114>(x);
  x = dpp_add_step<0x118>(x);
  x = dpp_add_step<0x142>(x);
  x = dpp_add_step<0x143>(x);
  return __int_as_float(__builtin_amdgcn_readlane(__float_as_int(x), 63));
}

// async global->LDS, 16B per lane; LDS dest = uniform base + lane*16
__device__ __forceinline__ void gl_lds16(const float* g, float* lds_base) {
  __builtin_amdgcn_global_load_lds(
      (const __attribute__((address_space(1))) unsigned int*)g,
      (__attribute__((address_space(3))) unsigned int*)lds_base, 16, 0, 0);
}

__global__ __launch_bounds__(256, 1) void hungarian_fused_kernel(
    const float* __restrict__ logits, const float* __restrict__ pboxes,
    const int* __restrict__ glabels, const float* __restrict__ gboxes,
    float* __restrict__ out, float inv_B)
{
  const int b = blockIdx.x, tid = threadIdx.x;
  const int lane = tid & 63, w = tid >> 6;

  __shared__ __align__(16) float s_nlp[NQP * NC];  // raw logits -> nlp in place
  __shared__ __align__(16) float s_pb[NQP * NC];   // pred boxes (7 dims)
  __shared__ __align__(16) float s_gb[NG * NC];    // gt boxes (7 dims)
  __shared__ __align__(16) int   s_glab[NG];
  __shared__ float s_u[NG + 1];                    // row potentials (1-based)
  __shared__ int   s_j1[NG];                       // per-row argmin column
  __shared__ int   s_claim[NQ];

  // ---- Phase A: async staging (25200B logits, 25200B pboxes, 2800B gb, 400B lab)
  {
    const float* Lg = logits + (size_t)b * NQ * NC;
    const float* Pg = pboxes + (size_t)b * NQ * NC;
    const float* Gg = gboxes + (size_t)b * NG * NC;
    const int*   Bg = glabels + (size_t)b * NG;
    #pragma unroll
    for (int t = 0; t < 7; t++) {
      int i = (t << 8) + tid;                     // 16B-chunk index
      if (i < (NQ * NC) / 4) {
        gl_lds16(Lg + i * 4, s_nlp + ((t << 8) + (w << 6)) * 4);
        gl_lds16(Pg + i * 4, s_pb  + ((t << 8) + (w << 6)) * 4);
      }
    }
    if (tid < (NG * NC) / 4) gl_lds16(Gg + tid * 4, s_gb + (w << 6) * 4);
    if (tid < NG / 4) gl_lds16((const float*)Bg + tid * 4, (float*)s_glab);
    // zero padded tail (queries 900..959) so nothing downstream sees garbage
    for (int i = tid; i < (NQP - NQ) * NC; i += 256) {
      s_nlp[NQ * NC + i] = 0.f; s_pb[NQ * NC + i] = 0.f;
    }
    for (int c = tid; c < NQ; c += 256) s_claim[c] = 0x7fffffff;
    if (tid == 0) s_u[0] = 0.f;
  }
  __syncthreads();

  // ---- Phase B: -log_softmax in place ----
  for (int q = tid; q < NQP; q += 256) {
    float x[NC];
    #pragma unroll
    for (int c = 0; c < NC; c++) x[c] = s_nlp[q * NC + c];
    float mx = x[0];
    #pragma unroll
    for (int c = 1; c < NC; c++) mx = fmaxf(mx, x[c]);
    float t[NC]; float se = 0.f;
    #pragma unroll
    for (int c = 0; c < NC; c++) { t[c] = x[c] - mx; se += __expf(t[c]); }
    float lg = __logf(se);
    #pragma unroll
    for (int c = 0; c < NC; c++) s_nlp[q * NC + c] = lg - t[c];
  }
  __syncthreads();

  // per-lane column xyz
  float cpx[KS], cpy[KS], cpz[KS];
  #pragma unroll
  for (int k = 0; k < KS; k++) {
    int c = (k << 6) + lane;
    cpx[k] = s_pb[c * NC + 0]; cpy[k] = s_pb[c * NC + 1]; cpz[k] = s_pb[c * NC + 2];
  }

  // ---- Phase C: row reduction (25 rows per wave) + greedy claims ----
  for (int rl = 0; rl < 25; rl++) {
    int r = w * 25 + rl;
    int lab = s_glab[r];
    float gx = s_gb[r * NC + 0], gy = s_gb[r * NC + 1], gz = s_gb[r * NC + 2];
    float lb = INFF; int bk = 0;
    #pragma unroll
    for (int k = 0; k < KS; k++) {
      int c = (k << 6) + lane;
      float nlp = s_nlp[c * NC + lab];
      float bs = fabsf(cpx[k] - gx) + fabsf(cpy[k] - gy); bs += fabsf(cpz[k] - gz);
      float cost = nlp + bs;
      if (c >= NQ) cost = INFF;
      bool bt = cost < lb;
      bk = bt ? k : bk;
      lb = fminf(lb, cost);
    }
    float m1 = wave_min_b(lb);
    unsigned long long msk = __ballot(lb == m1);
    int src = (int)__builtin_ctzll(msk);
    int cstar = __builtin_amdgcn_readlane((bk << 6) | lane, src);  // 0-based col
    if (lane == 0) {
      s_u[r + 1] = m1;
      s_j1[r] = cstar;
      atomicMin(&s_claim[cstar], r + 1);   // winner = lowest row (1-based)
    }
  }
  __syncthreads();
  if (w != 0) return;   // only wave 0 past this point

  // ---- wave 0: row data into registers (rows lane and 64+lane) ----
  int   rlab0 = s_glab[lane];
  float rgx0 = s_gb[lane * NC + 0], rgy0 = s_gb[lane * NC + 1], rgz0 = s_gb[lane * NC + 2];
  int   rlab1 = 0; float rgx1 = 0.f, rgy1 = 0.f, rgz1 = 0.f;
  if (lane < NG - 64) {
    int r = 64 + lane;
    rlab1 = s_glab[r];
    rgx1 = s_gb[r * NC + 0]; rgy1 = s_gb[r * NC + 1]; rgz1 = s_gb[r * NC + 2];
  }

  int j10 = s_j1[lane];
  int j11 = (lane < NG - 64) ? s_j1[64 + lane] : 0;
  bool lose0 = (s_claim[j10] != lane + 1);
  bool lose1 = (lane < NG - 64) && (s_claim[j11] != lane + 65);
  unsigned long long fm0 = __ballot(lose0);
  unsigned long long fm1 = __ballot(lose1);

  int p[KS];
  #pragma unroll
  for (int k = 0; k < KS; k++) {
    int c = (k << 6) + lane;
    int wv = (c < NQ) ? s_claim[c] : 0x7fffffff;
    p[k] = (wv == 0x7fffffff) ? 0 : wv;
  }

  volatile float* vu = s_u;
  float v[KS];
  #pragma unroll
  for (int k = 0; k < KS; k++) v[k] = (((k << 6) + lane) < NQ) ? 0.f : -INFF;

  // ---- Phase D1: augmenting row reduction (1 scan per free row) ----
  {
    int steps = 0;
    while ((fm0 | fm1) && steps < 300) {
      steps++;
      int rfree;
      if (fm0) { int bit = (int)__builtin_ctzll(fm0); fm0 &= fm0 - 1; rfree = bit + 1; }
      else     { int bit = (int)__builtin_ctzll(fm1); fm1 &= fm1 - 1; rfree = bit + 65; }
      int ro = rfree - 1, rown = ro & 63, rslot = ro >> 6;
      int   lab = __builtin_amdgcn_readlane(rslot ? rlab1 : rlab0, rown);
      float gx = readlane_f(rslot ? rgx1 : rgx0, rown);
      float gy = readlane_f(rslot ? rgy1 : rgy0, rown);
      float gz = readlane_f(rslot ? rgz1 : rgz0, rown);

      float m1 = INFF, m2 = INFF; int bk = 0;
      #pragma unroll
      for (int k = 0; k < KS; k++) {
        int c = (k << 6) + lane;
        float nlp = s_nlp[c * NC + lab];
        float bs = fabsf(cpx[k] - gx) + fabsf(cpy[k] - gy); bs += fabsf(cpz[k] - gz);
        float rr = (nlp + bs) - v[k];     // invalid cols: v=-INF -> rr=+INF
        bool lt1 = rr < m1;
        m2 = lt1 ? m1 : fminf(m2, rr);
        m1 = fminf(m1, rr);
        bk = lt1 ? k : bk;
      }
      float m1w = wave_min_b(m1);
      unsigned long long msk = __ballot(m1 == m1w);
      int src = (int)__builtin_ctzll(msk);
      int cstar = __builtin_amdgcn_readlane((bk << 6) | lane, src);  // 0-based
      float x2 = (lane == src) ? m2 : m1;
      float m2w = wave_min_b(x2);

      if (lane == 0) vu[rfree] = m2w;     // u[i] = second min
      int cown = cstar & 63, cslot = cstar >> 6;
      int pc = 0;
      #pragma unroll
      for (int k = 0; k < KS; k++) if (k == cslot) pc = p[k];
      int oldp = __builtin_amdgcn_readlane(pc, cown);
      #pragma unroll
      for (int k = 0; k < KS; k++)
        if (k == cslot && lane == cown) {
          v[k] -= (m2w - m1w);            // keep reduced cost of new match at 0
          p[k] = rfree;
        }
      if (oldp > 0) {                     // displaced row rejoins free list
        if (oldp <= 64) fm0 |= 1ull << (oldp - 1);
        else            fm1 |= 1ull << (oldp - 65);
      }
    }
  }

  // ---- Phase D2: JV Dijkstra for leftovers (usually none) ----
  float vmask[KS], ds[KS], dfrz[KS];
  int way[KS];
  for (int half = 0; half < 2; half++) {
    unsigned long long fm = half ? fm1 : fm0;
    while (fm) {
      int bit = (int)__builtin_ctzll(fm);
      fm &= fm - 1;
      int rfree = bit + (half ? 65 : 1);       // 1-based row
      #pragma unroll
      for (int k = 0; k < KS; k++) { ds[k] = INFF; way[k] = 0; vmask[k] = v[k]; }
      unsigned usedm = 0;
      int i0 = rfree, j0v = 0, jf = -1;
      float minVal = 0.f;

      for (int it = 0; it < 1024; it++) {
        int ro = i0 - 1, rown = ro & 63, rslot = ro >> 6;
        int   lab = __builtin_amdgcn_readlane(rslot ? rlab1 : rlab0, rown);
        float gx = readlane_f(rslot ? rgx1 : rgx0, rown);
        float gy = readlane_f(rslot ? rgy1 : rgy0, rown);
        float gz = readlane_f(rslot ? rgz1 : rgz0, rown);
        float u_i0 = vu[i0];
        float hs = minVal - u_i0;

        float lb = INFF; int bk = 0;
        #pragma unroll
        for (int k = 0; k < KS; k++) {
          int c = (k << 6) + lane;
          float nlp = s_nlp[c * NC + lab];
          float bs = fabsf(cpx[k] - gx) + fabsf(cpy[k] - gy); bs += fabsf(cpz[k] - gz);
          float cost = nlp + bs;
          float rr = (cost + hs) - vmask[k];
          bool imp = rr < ds[k];
          way[k] = imp ? j0v : way[k];
          ds[k] = fminf(ds[k], rr);
          bool bt = ds[k] < lb;
          bk = bt ? k : bk;
          lb = fminf(lb, ds[k]);
        }
        float mn = wave_min_b(lb);
        unsigned long long msk = __ballot(lb == mn);
        int src = (int)__builtin_ctzll(msk);
        int cstar = __builtin_amdgcn_readlane((bk << 6) | lane, src);  // 0-based
        minVal = mn;

        int cown = cstar & 63, cslot = cstar >> 6;
        int pc = 0;
        #pragma unroll
        for (int k = 0; k < KS; k++) if (k == cslot) pc = p[k];
        int pv = __builtin_amdgcn_readlane(pc, cown);
        if (pv == 0) { jf = cstar; break; }
        #pragma unroll
        for (int k = 0; k < KS; k++)
          if (k == cslot && lane == cown) {
            vmask[k] = -INFF; ds[k] = INFF; dfrz[k] = minVal; usedm |= (1u << k);
          }
        i0 = pv; j0v = cstar + 1;                // way stores 1-based prev col
      }

      if (jf >= 0) {
        if (lane == 0) vu[rfree] += minVal;
        #pragma unroll
        for (int k = 0; k < KS; k++)
          if (usedm & (1u << k)) {
            float a = minVal - dfrz[k];
            v[k] -= a;
            vu[p[k]] += a;                       // distinct rows -> race-free
          }
        __threadfence_block();
        int jcur = jf;
        for (int it2 = 0; it2 < 1024; it2++) {
          int co = jcur & 63, cs = jcur >> 6;
          int wc = 0;
          #pragma unroll
          for (int k = 0; k < KS; k++) if (k == cs) wc = way[k];
          int wprev = __builtin_amdgcn_readlane(wc, co);
          int pnew;
          if (wprev == 0) pnew = rfree;
          else {
            int c2 = wprev - 1, co2 = c2 & 63, cs2 = c2 >> 6;
            int pc2 = 0;
            #pragma unroll
            for (int k = 0; k < KS; k++) if (k == cs2) pc2 = p[k];
            pnew = __builtin_amdgcn_readlane(pc2, co2);
          }
          #pragma unroll
          for (int k = 0; k < KS; k++) if (k == cs && lane == co) p[k] = pnew;
          if (wprev == 0) break;
          jcur = wprev - 1;
        }
      }
      __threadfence_block();
    }
  }

  // ---- Phase E: matched loss ----
  float ce = 0.f, l1 = 0.f;
  #pragma unroll
  for (int k = 0; k < KS; k++) {
    int c = (k << 6) + lane;
    int pr = p[k];
    if (c < NQ && pr > 0) {
      int g = pr - 1;
      ce += s_nlp[c * NC + s_glab[g]];
      float s = 0.f;
      #pragma unroll
      for (int d7 = 0; d7 < 7; d7++) s += fabsf(s_pb[c * NC + d7] - s_gb[g * NC + d7]);
      l1 += s;
    }
  }
  float tot = ce * (1.f / NG) + l1 * (1.f / (NG * 7.f));
  tot = wave_sum_b(tot);
  if (lane == 0) atomicAdd(out, tot * inv_B);
}

extern "C" void kernel_launch(void* const* d_in, const int* in_sizes, int n_in,
                              void* d_out, int out_size, void* d_ws, size_t ws_size,
                              hipStream_t stream) {
  const float* logits  = (const float*)d_in[0];
  const float* pboxes  = (const float*)d_in[1];
  const int*   glabels = (const int*)d_in[2];
  const float* gboxes  = (const float*)d_in[3];
  float* out = (float*)d_out;
  const int B = in_sizes[0] / (NQ * NC);     // 128

  hipMemsetAsync(out, 0, sizeof(float), stream);
  hungarian_fused_kernel<<<dim3(B), dim3(256), 0, stream>>>(
      logits, pboxes, glabels, gboxes, out, 1.0f / (float)B);
}

// Round 5
// 150.833 us; speedup vs baseline: 2.6794x; 2.6794x over previous
//
#include <hip/hip_runtime.h>
#include <math.h>

// HungarianLoss, fused single kernel. One block (256 threads = 4 waves) per
// batch element. Column ownership is lane-major: lane L (0..59) owns columns
// c = L*15 + t, t in [0,15); slot 15 is an +INF pad so scans run 16 slots.
// nlp is stored transposed+padded: s_nlpT[class*1280 + lane*20 + t] so a scan
// is 4 conflict-free ds_read_b128. p[col] (matched row) and pu[col]=u[p[col]]
// live in LDS; the Dijkstra hot loop reads both with one broadcast pair.
// Phase D algorithm = R2/R3's verified JV shortest-augmenting-path with
// deferred dual updates (absmax 0.0 on HW).

#define NQ   900
#define NQP  960
#define NG   100
#define NC   7
#define SL   16      // scan slots per lane
#define CPL  15      // real columns per lane (lanes 0..59)
#define NSTR 20      // per-lane stride in s_nlpT (words; 16B aligned, bank-clean)
#define INFF __builtin_inff()

__device__ __forceinline__ float readlane_f(float x, int l) {
  return __int_as_float(__builtin_amdgcn_readlane(__float_as_int(x), l));
}
__device__ __forceinline__ float rfl_f(float x) {
  return __int_as_float(__builtin_amdgcn_readfirstlane(__float_as_int(x)));
}

template<int CTRL>
__device__ __forceinline__ float dpp_min_step(float x) {
  int y = __builtin_amdgcn_update_dpp(__float_as_int(x), __float_as_int(x),
                                      CTRL, 0xf, 0xf, false);
  return fminf(x, __int_as_float(y));
}
__device__ __forceinline__ float wave_min_b(float x) {
  x = dpp_min_step<0x111>(x);
  x = dpp_min_step<0x112>(x);
  x = dpp_min_step<0x114>(x);
  x = dpp_min_step<0x118>(x);
  x = dpp_min_step<0x142>(x);
  x = dpp_min_step<0x143>(x);
  return __int_as_float(__builtin_amdgcn_readlane(__float_as_int(x), 63));
}
template<int CTRL>
__device__ __forceinline__ float dpp_add_step(float x) {
  int y = __builtin_amdgcn_update_dpp(0, __float_as_int(x),
                                      CTRL, 0xf, 0xf, true);
  return x + __int_as_float(y);
}
__device__ __forceinline__ float wave_sum_b(float x) {
  x = dpp_add_step<0x111>(x);
  x = dpp_add_step<0x112>(x);
  x = dpp_add_step<0x114>(x);
  x = dpp_add_step<0x118>(x);
  x = dpp_add_step<0x142>(x);
  x = dpp_add_step<0x143>(x);
  return __int_as_float(__builtin_amdgcn_readlane(__float_as_int(x), 63));
}

__device__ __forceinline__ void gl_lds16(const float* g, float* lds_base) {
  __builtin_amdgcn_global_load_lds(
      (const __attribute__((address_space(1))) unsigned int*)g,
      (__attribute__((address_space(3))) unsigned int*)lds_base, 16, 0, 0);
}

__global__ __launch_bounds__(256, 1) void hungarian_fused_kernel(
    const float* __restrict__ logits, const float* __restrict__ pboxes,
    const int* __restrict__ glabels, const float* __restrict__ gboxes,
    float* __restrict__ out, float inv_B)
{
  const int b = blockIdx.x, tid = threadIdx.x;
  const int lane = tid & 63, w = tid >> 6;

  __shared__ __align__(16) float s_raw[NQ * NC];       // raw logits
  __shared__ __align__(16) float s_nlpT[NC * 1280];    // transposed nlp
  __shared__ __align__(16) float s_pb[NQP * NC];       // pred boxes
  __shared__ __align__(16) float s_gb[NG * NC];        // gt boxes
  __shared__ __align__(16) int   s_glab[NG];
  __shared__ float s_u[NG + 1];                        // row duals (1-based)
  __shared__ int   s_j1[NG];                           // per-row argmin col
  __shared__ int   s_p[NQ];                            // col -> matched row
  __shared__ float s_pu[NQ];                           // pu[c] = u[p[c]]

  // ---- Phase A: async staging ----
  {
    const float* Lg = logits + (size_t)b * NQ * NC;
    const float* Pg = pboxes + (size_t)b * NQ * NC;
    const float* Gg = gboxes + (size_t)b * NG * NC;
    const int*   Bg = glabels + (size_t)b * NG;
    #pragma unroll
    for (int t = 0; t < 7; t++) {
      int i = (t << 8) + tid;
      if (i < (NQ * NC) / 4) {
        gl_lds16(Lg + i * 4, s_raw + ((t << 8) + (w << 6)) * 4);
        gl_lds16(Pg + i * 4, s_pb  + ((t << 8) + (w << 6)) * 4);
      }
    }
    if (tid < (NG * NC) / 4) gl_lds16(Gg + tid * 4, s_gb + (w << 6) * 4);
    if (tid < NG / 4) gl_lds16((const float*)Bg + tid * 4, (float*)s_glab);
    for (int i = tid; i < (NQP - NQ) * NC; i += 256) s_pb[NQ * NC + i] = 0.f;
    for (int c = tid; c < NQ; c += 256) s_p[c] = 0x7fffffff;
    if (tid == 0) s_u[0] = 0.f;
  }
  __syncthreads();

  // ---- Phase B: -log_softmax into transposed layout ----
  for (int q = tid; q < NQP; q += 256) {
    float o[NC];
    if (q < NQ) {
      float x[NC];
      #pragma unroll
      for (int c = 0; c < NC; c++) x[c] = s_raw[q * NC + c];
      float mx = x[0];
      #pragma unroll
      for (int c = 1; c < NC; c++) mx = fmaxf(mx, x[c]);
      float tt[NC]; float se = 0.f;
      #pragma unroll
      for (int c = 0; c < NC; c++) { tt[c] = x[c] - mx; se += __expf(tt[c]); }
      float lg = __logf(se);
      #pragma unroll
      for (int c = 0; c < NC; c++) o[c] = lg - tt[c];
    } else {
      #pragma unroll
      for (int c = 0; c < NC; c++) o[c] = 0.f;
    }
    int Lq = q / CPL, tq = q - Lq * CPL;
    int base = Lq * NSTR + tq;
    #pragma unroll
    for (int c = 0; c < NC; c++) s_nlpT[c * 1280 + base] = o[c];
  }
  // pad slot t=15 := +INF
  for (int i = tid; i < NC * 64; i += 256) {
    int cl = i >> 6, LL = i & 63;
    s_nlpT[cl * 1280 + LL * NSTR + CPL] = INFF;
  }
  __syncthreads();

  // validity template + per-lane column xyz
  const bool lval = (lane < NQ / CPL);    // lanes 0..59 own columns
  float vini[SL];
  #pragma unroll
  for (int t = 0; t < SL; t++) vini[t] = (lval && t < CPL) ? 0.f : -INFF;
  float cpx[SL], cpy[SL], cpz[SL];
  #pragma unroll
  for (int t = 0; t < SL; t++) { cpx[t] = 0.f; cpy[t] = 0.f; cpz[t] = 0.f; }
  if (lval) {
    #pragma unroll
    for (int t = 0; t < CPL; t++) {
      int c = lane * CPL + t;
      cpx[t] = s_pb[c * NC + 0]; cpy[t] = s_pb[c * NC + 1]; cpz[t] = s_pb[c * NC + 2];
    }
  }

  // ---- Phase C: row reduction + greedy claims (25 rows per wave) ----
  for (int rl = 0; rl < 25; rl++) {
    int r = w * 25 + rl;
    int lab = s_glab[r];
    float gx = s_gb[r * NC + 0], gy = s_gb[r * NC + 1], gz = s_gb[r * NC + 2];
    const float4* np4 = (const float4*)&s_nlpT[lab * 1280 + lane * NSTR];
    float4 q0 = np4[0], q1 = np4[1], q2 = np4[2], q3 = np4[3];
    float nl[SL] = {q0.x,q0.y,q0.z,q0.w, q1.x,q1.y,q1.z,q1.w,
                    q2.x,q2.y,q2.z,q2.w, q3.x,q3.y,q3.z,q3.w};
    float lb = INFF; int bk = 0;
    #pragma unroll
    for (int t = 0; t < SL; t++) {
      float bs = fabsf(cpx[t] - gx) + fabsf(cpy[t] - gy); bs += fabsf(cpz[t] - gz);
      float cost = (nl[t] + bs) - vini[t];
      bool bt = cost < lb;
      bk = bt ? t : bk;
      lb = fminf(lb, cost);
    }
    float m1 = wave_min_b(lb);
    unsigned long long msk = __ballot(lb == m1);
    int src = (int)__builtin_ctzll(msk);
    int cpk = __builtin_amdgcn_readlane((bk << 6) | lane, src);
    if (lane == 0) {
      int cc = (cpk & 63) * CPL + (cpk >> 6);
      s_u[r + 1] = m1;
      s_j1[r] = cc;
      atomicMin(&s_p[cc], r + 1);
    }
  }
  __syncthreads();
  if (w != 0) return;   // wave 0 only from here

  volatile float* vu = s_u;

  // finalize p (sentinel -> 0), build pu
  if (lval) {
    #pragma unroll
    for (int t = 0; t < CPL; t++) {
      int c = lane * CPL + t;
      int pv = s_p[c];
      if (pv == 0x7fffffff) { pv = 0; s_p[c] = 0; }
      s_pu[c] = (pv > 0) ? s_u[pv] : 0.f;
    }
  }

  // free-row masks
  int j1a = s_j1[lane];
  bool lose0 = (s_p[j1a] != lane + 1);
  bool lose1 = false;
  if (lane < NG - 64) {
    int j1b = s_j1[64 + lane];
    lose1 = (s_p[j1b] != lane + 65);
  }
  unsigned long long fm0 = __ballot(lose0);
  unsigned long long fm1 = __ballot(lose1);

  // row data in registers: lane holds rows lane (slot0) and 64+lane (slot1)
  int   rlab0 = s_glab[lane];
  float rgx0 = s_gb[lane * NC + 0], rgy0 = s_gb[lane * NC + 1], rgz0 = s_gb[lane * NC + 2];
  int   rlab1 = 0; float rgx1 = 0.f, rgy1 = 0.f, rgz1 = 0.f;
  if (lane < NG - 64) {
    int r = 64 + lane;
    rlab1 = s_glab[r];
    rgx1 = s_gb[r * NC + 0]; rgy1 = s_gb[r * NC + 1]; rgz1 = s_gb[r * NC + 2];
  }

  float v[SL];
  #pragma unroll
  for (int t = 0; t < SL; t++) v[t] = vini[t];

  float ds[SL]; int way[SL];

  // ---- Phase D: JV shortest augmenting paths ----
  for (int half = 0; half < 2; half++) {
    unsigned long long fm = half ? fm1 : fm0;
    while (fm) {
      int bit = (int)__builtin_ctzll(fm);
      fm &= fm - 1;
      int rfree = bit + (half ? 65 : 1);           // 1-based row
      #pragma unroll
      for (int t = 0; t < SL; t++) { ds[t] = INFF; way[t] = 0; }
      unsigned usedm = 0;
      int i0 = rfree;
      float u_i0 = vu[rfree];
      int j0p = 0;                                 // packed prev col + 1
      float minVal = 0.f;
      int jfpk = -1;

      for (int it = 0; it < 960; it++) {
        int ro = i0 - 1, rown = ro & 63, rslot = ro >> 6;
        int   lab = __builtin_amdgcn_readlane(rslot ? rlab1 : rlab0, rown);
        float gx = readlane_f(rslot ? rgx1 : rgx0, rown);
        float gy = readlane_f(rslot ? rgy1 : rgy0, rown);
        float gz = readlane_f(rslot ? rgz1 : rgz0, rown);
        float hs = minVal - u_i0;

        const float4* np4 = (const float4*)&s_nlpT[lab * 1280 + lane * NSTR];
        float4 q0 = np4[0], q1 = np4[1], q2 = np4[2], q3 = np4[3];
        float nl[SL] = {q0.x,q0.y,q0.z,q0.w, q1.x,q1.y,q1.z,q1.w,
                        q2.x,q2.y,q2.z,q2.w, q3.x,q3.y,q3.z,q3.w};

        float lb = INFF; int bk = 0;
        #pragma unroll
        for (int t = 0; t < SL; t++) {
          float bs = fabsf(cpx[t] - gx) + fabsf(cpy[t] - gy); bs += fabsf(cpz[t] - gz);
          float rr = ((nl[t] + bs) + hs) - v[t];
          bool ub = (usedm >> t) & 1u;
          rr = ub ? INFF : rr;
          bool imp = rr < ds[t];
          way[t] = imp ? j0p : way[t];
          ds[t] = fminf(ds[t], rr);
          float cand = ub ? INFF : ds[t];
          bool bt = cand < lb;
          bk = bt ? t : bk;
          lb = fminf(lb, cand);
        }
        float mn = wave_min_b(lb);
        unsigned long long msk = __ballot(lb == mn);
        int src = (int)__builtin_ctzll(msk);
        int cpk = __builtin_amdgcn_readlane((bk << 6) | lane, src);
        minVal = mn;

        int LL = cpk & 63, tt = cpk >> 6;
        int cc = LL * CPL + tt;
        int pv = __builtin_amdgcn_readfirstlane(s_p[cc]);
        float puv = rfl_f(s_pu[cc]);
        if (pv == 0) { jfpk = cpk; break; }
        usedm |= (lane == LL) ? (1u << tt) : 0u;
        i0 = pv; u_i0 = puv; j0p = cpk + 1;
      }

      if (jfpk >= 0) {
        // deferred dual updates; ds[used] froze at that column's distance
        if (lane == 0) vu[rfree] += minVal;
        #pragma unroll
        for (int t = 0; t < CPL; t++) {
          if ((usedm >> t) & 1u) {
            int c = lane * CPL + t;
            float a = minVal - ds[t];
            v[t] -= a;
            int ri = s_p[c];
            vu[ri] += a;                           // distinct rows: race-free
          }
        }
        __threadfence_block();
        #pragma unroll
        for (int t = 0; t < CPL; t++) {
          if ((usedm >> t) & 1u) {
            int c = lane * CPL + t;
            s_pu[c] = vu[s_p[c]];
          }
        }
        // augment along way (packed ids; way value +1, 0 = root)
        int jpk = jfpk;
        for (int g2 = 0; g2 < 256; g2++) {
          int LL = jpk & 63, tt = jpk >> 6;
          int cc = LL * CPL + tt;
          int wsel = 0;
          #pragma unroll
          for (int k = 0; k < SL; k++) if (k == tt) wsel = way[k];
          int wprev = __builtin_amdgcn_readlane(wsel, LL);
          int pnew;
          if (wprev == 0) pnew = rfree;
          else {
            int c2 = wprev - 1;
            pnew = s_p[(c2 & 63) * CPL + (c2 >> 6)];
          }
          pnew = __builtin_amdgcn_readfirstlane(pnew);
          if (lane == 0) { s_p[cc] = pnew; s_pu[cc] = vu[pnew]; }
          if (wprev == 0) break;
          jpk = wprev - 1;
        }
        __threadfence_block();
      }
    }
  }

  // ---- Phase E: matched loss ----
  float ce = 0.f, l1 = 0.f;
  if (lval) {
    #pragma unroll
    for (int t = 0; t < CPL; t++) {
      int c = lane * CPL + t;
      int pr = s_p[c];
      if (pr > 0) {
        int g = pr - 1;
        int lg = s_glab[g];
        ce += s_nlpT[lg * 1280 + lane * NSTR + t];
        float s = 0.f;
        #pragma unroll
        for (int d7 = 0; d7 < 7; d7++) s += fabsf(s_pb[c * NC + d7] - s_gb[g * NC + d7]);
        l1 += s;
      }
    }
  }
  float tot = ce * (1.f / NG) + l1 * (1.f / (NG * 7.f));
  tot = wave_sum_b(tot);
  if (lane == 0) atomicAdd(out, tot * inv_B);
}

extern "C" void kernel_launch(void* const* d_in, const int* in_sizes, int n_in,
                              void* d_out, int out_size, void* d_ws, size_t ws_size,
                              hipStream_t stream) {
  const float* logits  = (const float*)d_in[0];
  const float* pboxes  = (const float*)d_in[1];
  const int*   glabels = (const int*)d_in[2];
  const float* gboxes  = (const float*)d_in[3];
  float* out = (float*)d_out;
  const int B = in_sizes[0] / (NQ * NC);     // 128

  hipMemsetAsync(out, 0, sizeof(float), stream);
  hungarian_fused_kernel<<<dim3(B), dim3(256), 0, stream>>>(
      logits, pboxes, glabels, gboxes, out, 1.0f / (float)B);
}

// Round 6
// 141.777 us; speedup vs baseline: 2.8506x; 1.0639x over previous
//
#include <hip/hip_runtime.h>
#include <math.h>

// HungarianLoss fused kernel. One block (256 thr = 4 waves) per batch.
//  A: global_load_lds staging.  B: -log_softmax -> transposed LDS layout.
//  C: per-row min/argmin (25 rows/wave) -> duals u, greedy claims (atomicMin).
//  C2: per-row top-2 minima over FREE columns (4-wave parallel).
//  D (wave 0): JV Dijkstra over MATCHED columns only (<=100, 2 reg slots/lane,
//     xyz + 7-class nlp + v + prow + pu all in VGPRs). Free columns all keep
//     v=0, so best-free distance = min over tree rows of (minfree(row)+hs) --
//     tracked as an O(1) scalar. Deferred dual updates as in the verified
//     R2/R5 algorithm (absmax 0.0 on HW); only data placement changed.
//  E (wave 0): matched CE + L1 loss, DPP reduce, atomicAdd.

#define NQ   900
#define NQP  960
#define NG   100
#define NC   7
#define SL   16
#define CPL  15
#define NSTR 20
#define INFF __builtin_inff()

__device__ __forceinline__ float readlane_f(float x, int l) {
  return __int_as_float(__builtin_amdgcn_readlane(__float_as_int(x), l));
}
template<int CTRL>
__device__ __forceinline__ float dpp_min_step(float x) {
  int y = __builtin_amdgcn_update_dpp(__float_as_int(x), __float_as_int(x),
                                      CTRL, 0xf, 0xf, false);
  return fminf(x, __int_as_float(y));
}
__device__ __forceinline__ float wave_min_b(float x) {
  x = dpp_min_step<0x111>(x);
  x = dpp_min_step<0x112>(x);
  x = dpp_min_step<0x114>(x);
  x = dpp_min_step<0x118>(x);
  x = dpp_min_step<0x142>(x);
  x = dpp_min_step<0x143>(x);
  return __int_as_float(__builtin_amdgcn_readlane(__float_as_int(x), 63));
}
template<int CTRL>
__device__ __forceinline__ float dpp_add_step(float x) {
  int y = __builtin_amdgcn_update_dpp(0, __float_as_int(x),
                                      CTRL, 0xf, 0xf, true);
  return x + __int_as_float(y);
}
__device__ __forceinline__ float wave_sum_b(float x) {
  x = dpp_add_step<0x111>(x);
  x = dpp_add_step<0x112>(x);
  x = dpp_add_step<0x114>(x);
  x = dpp_add_step<0x118>(x);
  x = dpp_add_step<0x142>(x);
  x = dpp_add_step<0x143>(x);
  return __int_as_float(__builtin_amdgcn_readlane(__float_as_int(x), 63));
}
__device__ __forceinline__ void gl_lds16(const float* g, float* lds_base) {
  __builtin_amdgcn_global_load_lds(
      (const __attribute__((address_space(1))) unsigned int*)g,
      (__attribute__((address_space(3))) unsigned int*)lds_base, 16, 0, 0);
}
__device__ __forceinline__ float sel7v(float a0,float a1,float a2,float a3,
                                       float a4,float a5,float a6,int lab){
  float r = a0;
  r = lab==1 ? a1 : r;  r = lab==2 ? a2 : r;  r = lab==3 ? a3 : r;
  r = lab==4 ? a4 : r;  r = lab==5 ? a5 : r;  r = lab==6 ? a6 : r;
  return r;
}

__global__ __launch_bounds__(256, 1) void hungarian_fused_kernel(
    const float* __restrict__ logits, const float* __restrict__ pboxes,
    const int* __restrict__ glabels, const float* __restrict__ gboxes,
    float* __restrict__ out, float inv_B)
{
  const int b = blockIdx.x, tid = threadIdx.x;
  const int lane = tid & 63, w = tid >> 6;

  __shared__ __align__(16) float s_raw[NQ * NC];
  __shared__ __align__(16) float s_nlpT[NC * 1280];
  __shared__ __align__(16) float s_pb[NQP * NC];
  __shared__ __align__(16) float s_gb[NG * NC];
  __shared__ __align__(16) int   s_glab[NG];
  __shared__ float s_u[NG + 1];
  __shared__ int   s_j1[NG];
  __shared__ int   s_p[NQ];
  __shared__ float s_f1v[NG]; __shared__ int s_f1c[NG];
  __shared__ float s_f2v[NG]; __shared__ int s_f2c[NG];
  __shared__ int   s_mlist[128];

  // ---- Phase A: async staging ----
  {
    const float* Lg = logits + (size_t)b * NQ * NC;
    const float* Pg = pboxes + (size_t)b * NQ * NC;
    const float* Gg = gboxes + (size_t)b * NG * NC;
    const int*   Bg = glabels + (size_t)b * NG;
    #pragma unroll
    for (int t = 0; t < 7; t++) {
      int i = (t << 8) + tid;
      if (i < (NQ * NC) / 4) {
        gl_lds16(Lg + i * 4, s_raw + ((t << 8) + (w << 6)) * 4);
        gl_lds16(Pg + i * 4, s_pb  + ((t << 8) + (w << 6)) * 4);
      }
    }
    if (tid < (NG * NC) / 4) gl_lds16(Gg + tid * 4, s_gb + (w << 6) * 4);
    if (tid < NG / 4) gl_lds16((const float*)Bg + tid * 4, (float*)s_glab);
    for (int i = tid; i < (NQP - NQ) * NC; i += 256) s_pb[NQ * NC + i] = 0.f;
    for (int c = tid; c < NQ; c += 256) s_p[c] = 0x7fffffff;
    if (tid == 0) s_u[0] = 0.f;
  }
  __syncthreads();

  // ---- Phase B: -log_softmax -> transposed layout ----
  for (int q = tid; q < NQP; q += 256) {
    float o[NC];
    if (q < NQ) {
      float x[NC];
      #pragma unroll
      for (int c = 0; c < NC; c++) x[c] = s_raw[q * NC + c];
      float mx = x[0];
      #pragma unroll
      for (int c = 1; c < NC; c++) mx = fmaxf(mx, x[c]);
      float tt[NC]; float se = 0.f;
      #pragma unroll
      for (int c = 0; c < NC; c++) { tt[c] = x[c] - mx; se += __expf(tt[c]); }
      float lg = __logf(se);
      #pragma unroll
      for (int c = 0; c < NC; c++) o[c] = lg - tt[c];
    } else {
      #pragma unroll
      for (int c = 0; c < NC; c++) o[c] = 0.f;
    }
    int Lq = q / CPL, tq = q - Lq * CPL;
    int base = Lq * NSTR + tq;
    #pragma unroll
    for (int c = 0; c < NC; c++) s_nlpT[c * 1280 + base] = o[c];
  }
  for (int i = tid; i < NC * 64; i += 256) {
    int cl = i >> 6, LL = i & 63;
    s_nlpT[cl * 1280 + LL * NSTR + CPL] = INFF;
  }
  __syncthreads();

  const bool lval = (lane < NQ / CPL);   // lanes 0..59 own 15 columns each
  float vini[SL];
  #pragma unroll
  for (int t = 0; t < SL; t++) vini[t] = (lval && t < CPL) ? 0.f : -INFF;
  float cpx[CPL], cpy[CPL], cpz[CPL];
  #pragma unroll
  for (int t = 0; t < CPL; t++) { cpx[t]=0.f; cpy[t]=0.f; cpz[t]=0.f; }
  if (lval) {
    #pragma unroll
    for (int t = 0; t < CPL; t++) {
      int c = lane * CPL + t;
      cpx[t]=s_pb[c*NC+0]; cpy[t]=s_pb[c*NC+1]; cpz[t]=s_pb[c*NC+2];
    }
  }

  // ---- Phase C: row reduction + greedy claims (25 rows/wave) ----
  for (int rl = 0; rl < 25; rl++) {
    int r = w * 25 + rl;
    int lab = s_glab[r];
    float gx = s_gb[r*NC+0], gy = s_gb[r*NC+1], gz = s_gb[r*NC+2];
    const float4* np4 = (const float4*)&s_nlpT[lab * 1280 + lane * NSTR];
    float4 q0 = np4[0], q1 = np4[1], q2 = np4[2], q3 = np4[3];
    float nl[SL] = {q0.x,q0.y,q0.z,q0.w, q1.x,q1.y,q1.z,q1.w,
                    q2.x,q2.y,q2.z,q2.w, q3.x,q3.y,q3.z,q3.w};
    float lb = INFF; int bk = 0;
    #pragma unroll
    for (int t = 0; t < SL; t++) {
      float bs = (t<CPL) ? (fabsf(cpx[t]-gx)+fabsf(cpy[t]-gy)+fabsf(cpz[t]-gz)) : 0.f;
      float cost = (nl[t] + bs) - vini[t];
      bool bt = cost < lb;
      bk = bt ? t : bk;
      lb = fminf(lb, cost);
    }
    float m1 = wave_min_b(lb);
    unsigned long long msk = __ballot(lb == m1);
    int src = (int)__builtin_ctzll(msk);
    int cpk = __builtin_amdgcn_readlane((bk << 6) | lane, src);
    if (lane == 0) {
      int cc = (cpk & 63) * CPL + (cpk >> 6);
      s_u[r + 1] = m1;
      s_j1[r] = cc;
      atomicMin(&s_p[cc], r + 1);
    }
  }
  __syncthreads();
  // finalize sentinels
  for (int c = tid; c < NQ; c += 256) if (s_p[c] == 0x7fffffff) s_p[c] = 0;
  __syncthreads();

  // free mask over owned columns
  unsigned fmask = 0;
  if (lval) {
    #pragma unroll
    for (int t = 0; t < CPL; t++) {
      int c = lane * CPL + t;
      if (s_p[c] == 0) fmask |= (1u << t);
    }
  }

  // top-2 over free columns for a given row (wave-wide helper)
  auto top2row = [&](int lab, float gx, float gy, float gz,
                     float &o1v, int &o1c, float &o2v, int &o2c) {
    const float4* np4 = (const float4*)&s_nlpT[lab * 1280 + lane * NSTR];
    float4 q0 = np4[0], q1 = np4[1], q2 = np4[2], q3 = np4[3];
    float nl[SL] = {q0.x,q0.y,q0.z,q0.w, q1.x,q1.y,q1.z,q1.w,
                    q2.x,q2.y,q2.z,q2.w, q3.x,q3.y,q3.z,q3.w};
    float m1 = INFF, m2 = INFF; int c1 = 0, c2 = 0;
    #pragma unroll
    for (int t = 0; t < CPL; t++) {
      float bs = fabsf(cpx[t]-gx)+fabsf(cpy[t]-gy)+fabsf(cpz[t]-gz);
      float cost = nl[t] + bs;
      bool valid = (fmask >> t) & 1u;
      cost = valid ? cost : INFF;
      bool lt1 = cost < m1;
      bool lt2 = cost < m2;
      c2 = lt1 ? c1 : (lt2 ? t : c2);
      m2 = lt1 ? m1 : fminf(m2, cost);
      c1 = lt1 ? t : c1;
      m1 = fminf(m1, cost);
    }
    float w1 = wave_min_b(m1);
    unsigned long long mk = __ballot(m1 == w1);
    int src = (int)__builtin_ctzll(mk);
    int col1 = __builtin_amdgcn_readlane(lane * CPL + c1, src);
    float alt = (lane == src) ? m2 : m1;
    int  altc = (lane == src) ? c2 : c1;
    float w2 = wave_min_b(alt);
    unsigned long long mk2 = __ballot(alt == w2);
    int src2 = (int)__builtin_ctzll(mk2);
    int col2 = __builtin_amdgcn_readlane(lane * CPL + altc, src2);
    o1v = w1; o1c = col1; o2v = w2; o2c = col2;
  };

  // ---- Phase C2: per-row top-2 free minima (25 rows/wave) ----
  for (int rl = 0; rl < 25; rl++) {
    int r = w * 25 + rl;
    int lab = s_glab[r];
    float gx = s_gb[r*NC+0], gy = s_gb[r*NC+1], gz = s_gb[r*NC+2];
    float v1, v2; int cc1, cc2;
    top2row(lab, gx, gy, gz, v1, cc1, v2, cc2);
    if (lane == 0) {
      s_f1v[r] = v1; s_f1c[r] = cc1; s_f2v[r] = v2; s_f2c[r] = cc2;
    }
  }
  __syncthreads();
  if (w != 0) return;                      // wave 0 only from here

  volatile float* vu = s_u;

  // ---- wave0 register state ----
  // rows: slot0 = row lane+1 (lanes 0..63), slot1 = row lane+65 (lanes 0..35)
  const bool r1ok = (lane < NG - 64);
  int   rlab0 = s_glab[lane];
  float rgx0 = s_gb[lane*NC+0], rgy0 = s_gb[lane*NC+1], rgz0 = s_gb[lane*NC+2];
  int   rlab1 = 0; float rgx1=0.f, rgy1=0.f, rgz1=0.f;
  if (r1ok) {
    int r = 64 + lane;
    rlab1 = s_glab[r];
    rgx1 = s_gb[r*NC+0]; rgy1 = s_gb[r*NC+1]; rgz1 = s_gb[r*NC+2];
  }
  float ru0 = vu[lane + 1];
  float ru1 = r1ok ? vu[lane + 65] : 0.f;
  float rf1v0 = s_f1v[lane];       int rf1c0 = s_f1c[lane];
  float rf2v0 = s_f2v[lane];       int rf2c0 = s_f2c[lane];
  float rf1v1 = r1ok ? s_f1v[64+lane] : INFF; int rf1c1 = r1ok ? s_f1c[64+lane] : -1;
  float rf2v1 = r1ok ? s_f2v[64+lane] : INFF; int rf2c1 = r1ok ? s_f2c[64+lane] : -1;

  // free-row masks
  bool lose0 = (s_p[s_j1[lane]] != lane + 1);
  bool lose1 = r1ok && (s_p[s_j1[64 + lane]] != lane + 65);
  unsigned long long fm0 = __ballot(lose0);
  unsigned long long fm1 = __ballot(lose1);

  // matched-column list (compaction via ballot prefix)
  int NM = 0;
  #pragma unroll
  for (int t = 0; t < CPL; t++) {
    int c = lane * CPL + t;
    bool has = lval && (s_p[c] > 0);
    unsigned long long m = __ballot(has);
    int pos = NM + (int)__popcll(m & ((1ull << lane) - 1ull));
    if (has) s_mlist[pos] = c;
    NM += (int)__popcll(m);
  }

  // slot registers: slot s = lane + 64k
  int   mcol[2]  = {-1,-1};
  int   mprow[2] = {0,0};
  float mpu[2]   = {0.f,0.f};
  float mv[2]    = {0.f,0.f};
  float mx[2]={0,0}, my[2]={0,0}, mz[2]={0,0};
  float mn0[2],mn1[2],mn2[2],mn3[2],mn4[2],mn5[2],mn6[2];
  #pragma unroll
  for (int k = 0; k < 2; k++) { mn0[k]=0;mn1[k]=0;mn2[k]=0;mn3[k]=0;mn4[k]=0;mn5[k]=0;mn6[k]=0; }
  #pragma unroll
  for (int k = 0; k < 2; k++) {
    int s = lane + (k << 6);
    if (s < NM) {
      int c = s_mlist[s];
      int cq = c / CPL, ct = c - cq * CPL;
      mcol[k] = c;
      mx[k] = s_pb[c*NC+0]; my[k] = s_pb[c*NC+1]; mz[k] = s_pb[c*NC+2];
      mn0[k] = s_nlpT[0*1280 + cq*NSTR + ct];
      mn1[k] = s_nlpT[1*1280 + cq*NSTR + ct];
      mn2[k] = s_nlpT[2*1280 + cq*NSTR + ct];
      mn3[k] = s_nlpT[3*1280 + cq*NSTR + ct];
      mn4[k] = s_nlpT[4*1280 + cq*NSTR + ct];
      mn5[k] = s_nlpT[5*1280 + cq*NSTR + ct];
      mn6[k] = s_nlpT[6*1280 + cq*NSTR + ct];
      mprow[k] = s_p[c];
      mpu[k] = vu[mprow[k]];
      mv[k] = 0.f;
    }
  }

  float dsl[2]; int wsl[2];

  // ---- Phase D: Dijkstra over matched columns ----
  for (int half = 0; half < 2; half++) {
    unsigned long long fm = half ? fm1 : fm0;
    while (fm) {
      int bit = (int)__builtin_ctzll(fm);
      fm &= fm - 1;
      int rfree = bit + (half ? 65 : 1);
      dsl[0] = INFF; dsl[1] = INFF; wsl[0] = 0; wsl[1] = 0;
      unsigned usedm = 0;
      float bfv = INFF; int bfc = -1, bfprev = 0;
      int i0 = rfree;
      int ro0 = rfree - 1;
      float u_i0 = readlane_f((ro0 >> 6) ? ru1 : ru0, ro0 & 63);
      int j0p = 0;
      float minVal = 0.f;
      int jf = -1, jfprev = 0;

      for (int it = 0; it < 128; it++) {
        int ro = i0 - 1, rown = ro & 63, rs = ro >> 6;
        int   lab = __builtin_amdgcn_readlane(rs ? rlab1 : rlab0, rown);
        float gx = readlane_f(rs ? rgx1 : rgx0, rown);
        float gy = readlane_f(rs ? rgy1 : rgy0, rown);
        float gz = readlane_f(rs ? rgz1 : rgz0, rown);
        float hs = minVal - u_i0;
        // best-free contribution from this row
        float f1v = readlane_f(rs ? rf1v1 : rf1v0, rown);
        int   f1c = __builtin_amdgcn_readlane(rs ? rf1c1 : rf1c0, rown);
        float cbf = f1v + hs;
        if (cbf < bfv) { bfv = cbf; bfc = f1c; bfprev = j0p; }
        // matched-column scan (2 slots)
        float lb = INFF; int bk = 0;
        #pragma unroll
        for (int k = 0; k < 2; k++) {
          bool gate = ((lane + (k << 6)) < NM) && !((usedm >> k) & 1u);
          float nl = sel7v(mn0[k],mn1[k],mn2[k],mn3[k],mn4[k],mn5[k],mn6[k],lab);
          float bs = fabsf(mx[k]-gx)+fabsf(my[k]-gy)+fabsf(mz[k]-gz);
          float rr = ((nl + bs) + hs) - mv[k];
          bool imp = gate && (rr < dsl[k]);
          dsl[k] = imp ? rr : dsl[k];
          wsl[k] = imp ? j0p : wsl[k];
          float cand = gate ? dsl[k] : INFF;
          bool bt = cand < lb;
          bk = bt ? k : bk;
          lb = fminf(lb, cand);
        }
        float dm = wave_min_b(lb);
        if (bfv <= dm) { minVal = bfv; jf = bfc; jfprev = bfprev; break; }
        unsigned long long msk = __ballot(lb == dm);
        int src = (int)__builtin_ctzll(msk);
        int spk = __builtin_amdgcn_readlane((bk << 6) | lane, src);  // slot id
        minVal = dm;
        int so = spk & 63, sk = spk >> 6;
        usedm |= (lane == so) ? (1u << sk) : 0u;
        i0  = __builtin_amdgcn_readlane(sk ? mprow[1] : mprow[0], so);
        u_i0 = readlane_f(sk ? mpu[1] : mpu[0], so);
        j0p = spk + 1;
      }
      if (jf < 0) { jf = bfc; jfprev = bfprev; minVal = bfv; }  // safety

      // ---- dual updates (old prow) ----
      if (lane == 0) vu[rfree] += minVal;
      #pragma unroll
      for (int k = 0; k < 2; k++) {
        if ((usedm >> k) & 1u) {
          float a = minVal - dsl[k];
          mv[k] -= a;
          vu[mprow[k]] += a;        // distinct rows: race-free
        }
      }
      __threadfence_block();

      // ---- augment walk (terminal col jf, predecessor slot-code jfprev) ----
      int pred = jfprev;
      int nr;
      if (pred == 0) nr = rfree;
      else {
        int s = pred - 1;
        nr = __builtin_amdgcn_readlane((s >> 6) ? mprow[1] : mprow[0], s & 63);
      }
      if (lane == 0) s_p[jf] = nr;
      // append terminal as new matched slot
      {
        int cq = jf / CPL, ct = jf - cq * CPL;
        float nx = s_pb[jf*NC+0], ny = s_pb[jf*NC+1], nz = s_pb[jf*NC+2];
        float a0 = s_nlpT[0*1280 + cq*NSTR + ct];
        float a1 = s_nlpT[1*1280 + cq*NSTR + ct];
        float a2 = s_nlpT[2*1280 + cq*NSTR + ct];
        float a3 = s_nlpT[3*1280 + cq*NSTR + ct];
        float a4 = s_nlpT[4*1280 + cq*NSTR + ct];
        float a5 = s_nlpT[5*1280 + cq*NSTR + ct];
        float a6 = s_nlpT[6*1280 + cq*NSTR + ct];
        int kk = NM >> 6;
        if (lane == (NM & 63)) {
          if (kk == 0) {
            mcol[0]=jf; mx[0]=nx; my[0]=ny; mz[0]=nz; mprow[0]=nr; mv[0]=0.f;
            mn0[0]=a0;mn1[0]=a1;mn2[0]=a2;mn3[0]=a3;mn4[0]=a4;mn5[0]=a5;mn6[0]=a6;
          } else {
            mcol[1]=jf; mx[1]=nx; my[1]=ny; mz[1]=nz; mprow[1]=nr; mv[1]=0.f;
            mn0[1]=a0;mn1[1]=a1;mn2[1]=a2;mn3[1]=a3;mn4[1]=a4;mn5[1]=a5;mn6[1]=a6;
          }
        }
        NM++;
      }
      while (pred) {
        int s = pred - 1, so = s & 63, sk = s >> 6;
        int np = __builtin_amdgcn_readlane(sk ? wsl[1] : wsl[0], so);
        int nr2;
        if (np == 0) nr2 = rfree;
        else {
          int s2 = np - 1;
          nr2 = __builtin_amdgcn_readlane((s2 >> 6) ? mprow[1] : mprow[0], s2 & 63);
        }
        int sc = __builtin_amdgcn_readlane(sk ? mcol[1] : mcol[0], so);
        if (lane == so) { if (sk) mprow[1] = nr2; else mprow[0] = nr2; }
        if (lane == 0) s_p[sc] = nr2;
        pred = np;
      }
      __threadfence_block();

      // refresh u/pu registers
      ru0 = vu[lane + 1];
      if (r1ok) ru1 = vu[lane + 65];
      #pragma unroll
      for (int k = 0; k < 2; k++)
        if ((lane + (k << 6)) < NM) mpu[k] = vu[mprow[k]];

      // ---- free-structure maintenance: column jf left the free set ----
      if (lane == (jf / CPL)) fmask &= ~(1u << (jf - (jf / CPL) * CPL));
      if (rf1c0 == jf) { rf1v0 = rf2v0; rf1c0 = rf2c0; rf2c0 = -1; rf2v0 = INFF; }
      else if (rf2c0 == jf) { rf2c0 = -1; rf2v0 = INFF; }
      if (rf1c1 == jf) { rf1v1 = rf2v1; rf1c1 = rf2c1; rf2c1 = -1; rf2v1 = INFF; }
      else if (rf2c1 == jf) { rf2c1 = -1; rf2v1 = INFF; }
      unsigned long long need0 = __ballot(rf1c0 < 0);
      unsigned long long need1 = __ballot(r1ok && (rf1c1 < 0));
      while (need0) {
        int rb = (int)__builtin_ctzll(need0); need0 &= need0 - 1;
        int lab = __builtin_amdgcn_readlane(rlab0, rb);
        float gx = readlane_f(rgx0, rb), gy = readlane_f(rgy0, rb), gz = readlane_f(rgz0, rb);
        float v1, v2; int cc1, cc2;
        top2row(lab, gx, gy, gz, v1, cc1, v2, cc2);
        if (lane == rb) { rf1v0=v1; rf1c0=cc1; rf2v0=v2; rf2c0=cc2; }
      }
      while (need1) {
        int rb = (int)__builtin_ctzll(need1); need1 &= need1 - 1;
        int lab = __builtin_amdgcn_readlane(rlab1, rb);
        float gx = readlane_f(rgx1, rb), gy = readlane_f(rgy1, rb), gz = readlane_f(rgz1, rb);
        float v1, v2; int cc1, cc2;
        top2row(lab, gx, gy, gz, v1, cc1, v2, cc2);
        if (lane == rb) { rf1v1=v1; rf1c1=cc1; rf2v1=v2; rf2c1=cc2; }
      }
    }
  }

  // ---- Phase E: matched loss ----
  float ce = 0.f, l1 = 0.f;
  if (lval) {
    #pragma unroll
    for (int t = 0; t < CPL; t++) {
      int c = lane * CPL + t;
      int pr = s_p[c];
      if (pr > 0) {
        int g = pr - 1;
        int lg = s_glab[g];
        ce += s_nlpT[lg * 1280 + lane * NSTR + t];
        float s = 0.f;
        #pragma unroll
        for (int d7 = 0; d7 < 7; d7++) s += fabsf(s_pb[c*NC+d7] - s_gb[g*NC+d7]);
        l1 += s;
      }
    }
  }
  float tot = ce * (1.f / NG) + l1 * (1.f / (NG * 7.f));
  tot = wave_sum_b(tot);
  if (lane == 0) atomicAdd(out, tot * inv_B);
}

extern "C" void kernel_launch(void* const* d_in, const int* in_sizes, int n_in,
                              void* d_out, int out_size, void* d_ws, size_t ws_size,
                              hipStream_t stream) {
  const float* logits  = (const float*)d_in[0];
  const float* pboxes  = (const float*)d_in[1];
  const int*   glabels = (const int*)d_in[2];
  const float* gboxes  = (const float*)d_in[3];
  float* out = (float*)d_out;
  const int B = in_sizes[0] / (NQ * NC);   // 128

  hipMemsetAsync(out, 0, sizeof(float), stream);
  hungarian_fused_kernel<<<dim3(B), dim3(256), 0, stream>>>(
      logits, pboxes, glabels, gboxes, out, 1.0f / (float)B);
}

// Round 7
// 130.957 us; speedup vs baseline: 3.0861x; 1.0826x over previous
//
#include <hip/hip_runtime.h>
#include <math.h>

// HungarianLoss fused kernel. One block (256 thr = 4 waves) per batch.
//  A: global_load_lds staging.
//  B: -log_softmax -> t-major LDS layout s_nlpT[cl][t][lane] (conflict-free).
//  C: per-row argmin (25 rows/wave) -> duals u, greedy claims (atomicMin).
//  AUCTION: bounded eps=0 parallel auction rounds: free rows bid (m1,m2 over
//     cost - v), award via 32-bit atomicMin pack, winner applies exact price
//     update v[j*] -= (m2-m1), u[i] = m2. Preserves exact dual feasibility.
//  C2: per-row top-2 minima over FREE columns (free cols always keep v=0).
//  D (wave 0): JV Dijkstra over MATCHED columns only (2 reg slots/lane);
//     best-free tracked O(1) via per-row minfree. Verified R6 structure.
//  E (wave 0): matched CE + L1 loss, DPP reduce, atomicAdd.

#define NQ   900
#define NG   100
#define NC   7
#define CPL  15
#define ROUNDS 12
#define INFF __builtin_inff()

__device__ __forceinline__ float readlane_f(float x, int l) {
  return __int_as_float(__builtin_amdgcn_readlane(__float_as_int(x), l));
}
template<int CTRL>
__device__ __forceinline__ float dpp_min_step(float x) {
  int y = __builtin_amdgcn_update_dpp(__float_as_int(x), __float_as_int(x),
                                      CTRL, 0xf, 0xf, false);
  return fminf(x, __int_as_float(y));
}
__device__ __forceinline__ float wave_min_b(float x) {
  x = dpp_min_step<0x111>(x);
  x = dpp_min_step<0x112>(x);
  x = dpp_min_step<0x114>(x);
  x = dpp_min_step<0x118>(x);
  x = dpp_min_step<0x142>(x);
  x = dpp_min_step<0x143>(x);
  return __int_as_float(__builtin_amdgcn_readlane(__float_as_int(x), 63));
}
template<int CTRL>
__device__ __forceinline__ float dpp_add_step(float x) {
  int y = __builtin_amdgcn_update_dpp(0, __float_as_int(x),
                                      CTRL, 0xf, 0xf, true);
  return x + __int_as_float(y);
}
__device__ __forceinline__ float wave_sum_b(float x) {
  x = dpp_add_step<0x111>(x);
  x = dpp_add_step<0x112>(x);
  x = dpp_add_step<0x114>(x);
  x = dpp_add_step<0x118>(x);
  x = dpp_add_step<0x142>(x);
  x = dpp_add_step<0x143>(x);
  return __int_as_float(__builtin_amdgcn_readlane(__float_as_int(x), 63));
}
__device__ __forceinline__ void gl_lds16(const float* g, float* lds_base) {
  __builtin_amdgcn_global_load_lds(
      (const __attribute__((address_space(1))) unsigned int*)g,
      (__attribute__((address_space(3))) unsigned int*)lds_base, 16, 0, 0);
}
__device__ __forceinline__ float sel7v(float a0,float a1,float a2,float a3,
                                       float a4,float a5,float a6,int lab){
  float r = a0;
  r = lab==1 ? a1 : r;  r = lab==2 ? a2 : r;  r = lab==3 ? a3 : r;
  r = lab==4 ? a4 : r;  r = lab==5 ? a5 : r;  r = lab==6 ? a6 : r;
  return r;
}

__global__ __launch_bounds__(256, 1) void hungarian_fused_kernel(
    const float* __restrict__ logits, const float* __restrict__ pboxes,
    const int* __restrict__ glabels, const float* __restrict__ gboxes,
    float* __restrict__ out, float inv_B)
{
  const int b = blockIdx.x, tid = threadIdx.x;
  const int lane = tid & 63, w = tid >> 6;

  __shared__ __align__(16) float s_raw[NQ * NC];
  __shared__ __align__(16) float s_nlpT[NC * 1024];   // cl*1024 + t*64 + L
  __shared__ __align__(16) float s_pb[960 * NC];
  __shared__ __align__(16) float s_gb[NG * NC];
  __shared__ __align__(16) int   s_glab[NG];
  __shared__ float s_u[NG + 1];
  __shared__ float s_v[CPL * 64];                     // t*64 + L
  __shared__ int   s_p[NQ];
  __shared__ unsigned s_bid[NQ];
  __shared__ int   s_rmatch[NG];
  __shared__ float s_bm1[NG], s_bm2[NG];
  __shared__ int   s_bc[NG];
  __shared__ int   s_freelist[NG];
  __shared__ int   s_nfree;
  __shared__ float s_f1v[NG]; __shared__ int s_f1c[NG];
  __shared__ float s_f2v[NG]; __shared__ int s_f2c[NG];
  __shared__ int   s_mlist[128];

  // ---- Phase A: async staging ----
  {
    const float* Lg = logits + (size_t)b * NQ * NC;
    const float* Pg = pboxes + (size_t)b * NQ * NC;
    const float* Gg = gboxes + (size_t)b * NG * NC;
    const int*   Bg = glabels + (size_t)b * NG;
    #pragma unroll
    for (int t = 0; t < 7; t++) {
      int i = (t << 8) + tid;
      if (i < (NQ * NC) / 4) {
        gl_lds16(Lg + i * 4, s_raw + ((t << 8) + (w << 6)) * 4);
        gl_lds16(Pg + i * 4, s_pb  + ((t << 8) + (w << 6)) * 4);
      }
    }
    if (tid < (NG * NC) / 4) gl_lds16(Gg + tid * 4, s_gb + (w << 6) * 4);
    if (tid < NG / 4) gl_lds16((const float*)Bg + tid * 4, (float*)s_glab);
    for (int i = tid; i < (960 - NQ) * NC; i += 256) s_pb[NQ * NC + i] = 0.f;
    for (int c = tid; c < NQ; c += 256) { s_p[c] = 0x7fffffff; s_bid[c] = 0xFFFFFFFFu; }
    for (int i = tid; i < CPL * 64; i += 256) s_v[i] = 0.f;
    if (tid == 0) s_u[0] = 0.f;
  }
  __syncthreads();

  // ---- Phase B: -log_softmax -> t-major ----
  for (int i = tid; i < 960; i += 256) {
    int L = i & 63, t = i >> 6;       // t in [0,15)
    int q = L * CPL + t;
    float o[NC];
    if (q < NQ) {
      float x[NC];
      #pragma unroll
      for (int c = 0; c < NC; c++) x[c] = s_raw[q * NC + c];
      float mx = x[0];
      #pragma unroll
      for (int c = 1; c < NC; c++) mx = fmaxf(mx, x[c]);
      float tt[NC]; float se = 0.f;
      #pragma unroll
      for (int c = 0; c < NC; c++) { tt[c] = x[c] - mx; se += __expf(tt[c]); }
      float lg = __logf(se);
      #pragma unroll
      for (int c = 0; c < NC; c++) o[c] = lg - tt[c];
    } else {
      #pragma unroll
      for (int c = 0; c < NC; c++) o[c] = INFF;   // invalid columns never win
    }
    #pragma unroll
    for (int c = 0; c < NC; c++) s_nlpT[c * 1024 + t * 64 + L] = o[c];
  }
  __syncthreads();

  const bool lval = (lane < NQ / CPL);   // lanes 0..59 own 15 columns each
  float cpx[CPL], cpy[CPL], cpz[CPL];
  #pragma unroll
  for (int t = 0; t < CPL; t++) {
    int c = lane * CPL + t;              // c<960; pads are zero
    cpx[t]=s_pb[c*NC+0]; cpy[t]=s_pb[c*NC+1]; cpz[t]=s_pb[c*NC+2];
  }

  // ---- Phase C: row reduction + greedy claims (25 rows/wave) ----
  for (int rl = 0; rl < 25; rl++) {
    int r = w * 25 + rl;
    int lab = s_glab[r];
    float gx = s_gb[r*NC+0], gy = s_gb[r*NC+1], gz = s_gb[r*NC+2];
    float m1 = INFF; int c1t = 0;
    #pragma unroll
    for (int t = 0; t < CPL; t++) {
      float nl = s_nlpT[lab*1024 + t*64 + lane];
      float bs = fabsf(cpx[t]-gx)+fabsf(cpy[t]-gy)+fabsf(cpz[t]-gz);
      float cost = nl + bs;
      bool lt1 = cost < m1;
      c1t = lt1 ? t : c1t;
      m1 = fminf(m1, cost);
    }
    float w1 = wave_min_b(m1);
    unsigned long long mk = __ballot(m1 == w1);
    int src = (int)__builtin_ctzll(mk);
    int col = __builtin_amdgcn_readlane(lane * CPL + c1t, src);
    if (lane == 0) {
      s_u[r + 1] = w1;
      s_bc[r] = col;
      atomicMin(&s_p[col], r + 1);
    }
  }
  __syncthreads();
  for (int c = tid; c < NQ; c += 256) if (s_p[c] == 0x7fffffff) s_p[c] = 0;
  if (tid < NG) {
    int c = s_bc[tid];
    s_rmatch[tid] = (s_p[c] == tid + 1) ? c + 1 : 0;
  }
  __syncthreads();

  // ---- Auction rounds (eps=0, bounded) ----
  for (int round = 0; round < ROUNDS; round++) {
    if (tid == 0) s_nfree = 0;
    __syncthreads();
    if (tid < NG && s_rmatch[tid] == 0) {
      int ix = atomicAdd(&s_nfree, 1);
      s_freelist[ix] = tid;
    }
    __syncthreads();
    int nf = s_nfree;
    if (nf == 0) break;
    // bidding: waves take rows round-robin
    for (int fi = w; fi < nf; fi += 4) {
      int r = s_freelist[fi];
      int lab = s_glab[r];
      float gx = s_gb[r*NC+0], gy = s_gb[r*NC+1], gz = s_gb[r*NC+2];
      float m1 = INFF, m2 = INFF; int c1t = 0;
      #pragma unroll
      for (int t = 0; t < CPL; t++) {
        float nl = s_nlpT[lab*1024 + t*64 + lane];
        float vv = s_v[t*64 + lane];
        float bs = fabsf(cpx[t]-gx)+fabsf(cpy[t]-gy)+fabsf(cpz[t]-gz);
        float cost = (nl + bs) - vv;
        bool lt1 = cost < m1;
        m2 = lt1 ? m1 : fminf(m2, cost);
        c1t = lt1 ? t : c1t;
        m1 = fminf(m1, cost);
      }
      float w1 = wave_min_b(m1);
      unsigned long long mk = __ballot(m1 == w1);
      int src = (int)__builtin_ctzll(mk);
      int col1 = __builtin_amdgcn_readlane(lane * CPL + c1t, src);
      float alt = (lane == src) ? m2 : m1;
      float w2 = wave_min_b(alt);
      if (lane == 0) {
        s_bm1[r] = w1; s_bm2[r] = w2; s_bc[r] = col1;
        atomicMin(&s_bid[col1],
                  (__float_as_uint(w1) & 0xFFFFFF80u) | (unsigned)(r + 1));
      }
    }
    __syncthreads();
    // awards (one winner per column; winner applies its own exact update)
    for (int fi = tid; fi < nf; fi += 256) {
      int r = s_freelist[fi];
      int c = s_bc[r];
      if ((s_bid[c] & 0x7Fu) == (unsigned)(r + 1)) {
        int dold = s_p[c];
        s_p[c] = r + 1;
        s_rmatch[r] = c + 1;
        if (dold > 0) s_rmatch[dold - 1] = 0;
        s_u[r + 1] = s_bm2[r];
        s_v[(c % CPL) * 64 + (c / CPL)] -= (s_bm2[r] - s_bm1[r]);
      }
    }
    __syncthreads();
    for (int fi = tid; fi < nf; fi += 256)
      s_bid[s_bc[s_freelist[fi]]] = 0xFFFFFFFFu;
    __syncthreads();
  }

  // free mask over owned columns (free cols all still have v=0)
  unsigned fmask = 0;
  if (lval) {
    #pragma unroll
    for (int t = 0; t < CPL; t++)
      if (s_p[lane * CPL + t] == 0) fmask |= (1u << t);
  }

  auto top2row = [&](int lab, float gx, float gy, float gz,
                     float &o1v, int &o1c, float &o2v, int &o2c) {
    float m1 = INFF, m2 = INFF; int c1 = 0, c2 = 0;
    #pragma unroll
    for (int t = 0; t < CPL; t++) {
      float nl = s_nlpT[lab*1024 + t*64 + lane];
      float bs = fabsf(cpx[t]-gx)+fabsf(cpy[t]-gy)+fabsf(cpz[t]-gz);
      float cost = nl + bs;
      cost = ((fmask >> t) & 1u) ? cost : INFF;
      bool lt1 = cost < m1;
      bool lt2 = cost < m2;
      c2 = lt1 ? c1 : (lt2 ? t : c2);
      m2 = lt1 ? m1 : fminf(m2, cost);
      c1 = lt1 ? t : c1;
      m1 = fminf(m1, cost);
    }
    float w1 = wave_min_b(m1);
    unsigned long long mk = __ballot(m1 == w1);
    int src = (int)__builtin_ctzll(mk);
    int col1 = __builtin_amdgcn_readlane(lane * CPL + c1, src);
    float alt = (lane == src) ? m2 : m1;
    int  altc = (lane == src) ? c2 : c1;
    float w2 = wave_min_b(alt);
    unsigned long long mk2 = __ballot(alt == w2);
    int src2 = (int)__builtin_ctzll(mk2);
    int col2 = __builtin_amdgcn_readlane(lane * CPL + altc, src2);
    o1v = w1; o1c = col1; o2v = w2; o2c = col2;
  };

  // ---- Phase C2: per-row top-2 free minima (25 rows/wave) ----
  for (int rl = 0; rl < 25; rl++) {
    int r = w * 25 + rl;
    int lab = s_glab[r];
    float gx = s_gb[r*NC+0], gy = s_gb[r*NC+1], gz = s_gb[r*NC+2];
    float v1, v2; int cc1, cc2;
    top2row(lab, gx, gy, gz, v1, cc1, v2, cc2);
    if (lane == 0) {
      s_f1v[r] = v1; s_f1c[r] = cc1; s_f2v[r] = v2; s_f2c[r] = cc2;
    }
  }
  __syncthreads();
  if (w != 0) return;                      // wave 0 only from here

  volatile float* vu = s_u;

  const bool r1ok = (lane < NG - 64);
  int   rlab0 = s_glab[lane];
  float rgx0 = s_gb[lane*NC+0], rgy0 = s_gb[lane*NC+1], rgz0 = s_gb[lane*NC+2];
  int   rlab1 = 0; float rgx1=0.f, rgy1=0.f, rgz1=0.f;
  if (r1ok) {
    int r = 64 + lane;
    rlab1 = s_glab[r];
    rgx1 = s_gb[r*NC+0]; rgy1 = s_gb[r*NC+1]; rgz1 = s_gb[r*NC+2];
  }
  float ru0 = vu[lane + 1];
  float ru1 = r1ok ? vu[lane + 65] : 0.f;
  float rf1v0 = s_f1v[lane];       int rf1c0 = s_f1c[lane];
  float rf2v0 = s_f2v[lane];       int rf2c0 = s_f2c[lane];
  float rf1v1 = r1ok ? s_f1v[64+lane] : INFF; int rf1c1 = r1ok ? s_f1c[64+lane] : -1;
  float rf2v1 = r1ok ? s_f2v[64+lane] : INFF; int rf2c1 = r1ok ? s_f2c[64+lane] : -1;

  bool lose0 = (s_rmatch[lane] == 0);
  bool lose1 = r1ok && (s_rmatch[64 + lane] == 0);
  unsigned long long fm0 = __ballot(lose0);
  unsigned long long fm1 = __ballot(lose1);

  // matched-column list
  int NM = 0;
  #pragma unroll
  for (int t = 0; t < CPL; t++) {
    int c = lane * CPL + t;
    bool has = lval && (s_p[c] > 0);
    unsigned long long m = __ballot(has);
    int pos = NM + (int)__popcll(m & ((1ull << lane) - 1ull));
    if (has) s_mlist[pos] = c;
    NM += (int)__popcll(m);
  }

  int   mcol[2]  = {-1,-1};
  int   mprow[2] = {0,0};
  float mpu[2]   = {0.f,0.f};
  float mv[2]    = {0.f,0.f};
  float mx[2]={0,0}, my[2]={0,0}, mz[2]={0,0};
  float mn0[2],mn1[2],mn2[2],mn3[2],mn4[2],mn5[2],mn6[2];
  #pragma unroll
  for (int k = 0; k < 2; k++) { mn0[k]=0;mn1[k]=0;mn2[k]=0;mn3[k]=0;mn4[k]=0;mn5[k]=0;mn6[k]=0; }
  #pragma unroll
  for (int k = 0; k < 2; k++) {
    int s = lane + (k << 6);
    if (s < NM) {
      int c = s_mlist[s];
      int cq = c / CPL, ct = c - cq * CPL;
      mcol[k] = c;
      mx[k] = s_pb[c*NC+0]; my[k] = s_pb[c*NC+1]; mz[k] = s_pb[c*NC+2];
      mn0[k] = s_nlpT[0*1024 + ct*64 + cq];
      mn1[k] = s_nlpT[1*1024 + ct*64 + cq];
      mn2[k] = s_nlpT[2*1024 + ct*64 + cq];
      mn3[k] = s_nlpT[3*1024 + ct*64 + cq];
      mn4[k] = s_nlpT[4*1024 + ct*64 + cq];
      mn5[k] = s_nlpT[5*1024 + ct*64 + cq];
      mn6[k] = s_nlpT[6*1024 + ct*64 + cq];
      mprow[k] = s_p[c];
      mpu[k] = vu[mprow[k]];
      mv[k] = s_v[ct * 64 + cq];
    }
  }

  float dsl[2]; int wsl[2];

  // ---- Phase D: Dijkstra over matched columns ----
  for (int half = 0; half < 2; half++) {
    unsigned long long fm = half ? fm1 : fm0;
    while (fm) {
      int bit = (int)__builtin_ctzll(fm);
      fm &= fm - 1;
      int rfree = bit + (half ? 65 : 1);
      dsl[0] = INFF; dsl[1] = INFF; wsl[0] = 0; wsl[1] = 0;
      unsigned usedm = 0;
      float bfv = INFF; int bfc = -1, bfprev = 0;
      int i0 = rfree;
      int ro0 = rfree - 1;
      float u_i0 = readlane_f((ro0 >> 6) ? ru1 : ru0, ro0 & 63);
      int j0p = 0;
      float minVal = 0.f;
      int jf = -1, jfprev = 0;

      for (int it = 0; it < 128; it++) {
        int ro = i0 - 1, rown = ro & 63, rs = ro >> 6;
        int   lab = __builtin_amdgcn_readlane(rs ? rlab1 : rlab0, rown);
        float gx = readlane_f(rs ? rgx1 : rgx0, rown);
        float gy = readlane_f(rs ? rgy1 : rgy0, rown);
        float gz = readlane_f(rs ? rgz1 : rgz0, rown);
        float hs = minVal - u_i0;
        float f1v = readlane_f(rs ? rf1v1 : rf1v0, rown);
        int   f1c = __builtin_amdgcn_readlane(rs ? rf1c1 : rf1c0, rown);
        float cbf = f1v + hs;
        if (cbf < bfv) { bfv = cbf; bfc = f1c; bfprev = j0p; }
        float lb = INFF; int bk = 0;
        #pragma unroll
        for (int k = 0; k < 2; k++) {
          bool gate = ((lane + (k << 6)) < NM) && !((usedm >> k) & 1u);
          float nl = sel7v(mn0[k],mn1[k],mn2[k],mn3[k],mn4[k],mn5[k],mn6[k],lab);
          float bs = fabsf(mx[k]-gx)+fabsf(my[k]-gy)+fabsf(mz[k]-gz);
          float rr = ((nl + bs) + hs) - mv[k];
          bool imp = gate && (rr < dsl[k]);
          dsl[k] = imp ? rr : dsl[k];
          wsl[k] = imp ? j0p : wsl[k];
          float cand = gate ? dsl[k] : INFF;
          bool bt = cand < lb;
          bk = bt ? k : bk;
          lb = fminf(lb, cand);
        }
        float dm = wave_min_b(lb);
        if (bfv <= dm) { minVal = bfv; jf = bfc; jfprev = bfprev; break; }
        unsigned long long msk = __ballot(lb == dm);
        int src = (int)__builtin_ctzll(msk);
        int spk = __builtin_amdgcn_readlane((bk << 6) | lane, src);
        minVal = dm;
        int so = spk & 63, sk = spk >> 6;
        usedm |= (lane == so) ? (1u << sk) : 0u;
        i0  = __builtin_amdgcn_readlane(sk ? mprow[1] : mprow[0], so);
        u_i0 = readlane_f(sk ? mpu[1] : mpu[0], so);
        j0p = spk + 1;
      }
      if (jf < 0) { jf = bfc; jfprev = bfprev; minVal = bfv; }

      // dual updates
      if (lane == 0) vu[rfree] += minVal;
      #pragma unroll
      for (int k = 0; k < 2; k++) {
        if ((usedm >> k) & 1u) {
          float a = minVal - dsl[k];
          mv[k] -= a;
          vu[mprow[k]] += a;
        }
      }
      __threadfence_block();

      // augment walk
      int pred = jfprev;
      int nr;
      if (pred == 0) nr = rfree;
      else {
        int s = pred - 1;
        nr = __builtin_amdgcn_readlane((s >> 6) ? mprow[1] : mprow[0], s & 63);
      }
      if (lane == 0) s_p[jf] = nr;
      {
        int cq = jf / CPL, ct = jf - cq * CPL;
        float nx = s_pb[jf*NC+0], ny = s_pb[jf*NC+1], nz = s_pb[jf*NC+2];
        float a0 = s_nlpT[0*1024 + ct*64 + cq];
        float a1 = s_nlpT[1*1024 + ct*64 + cq];
        float a2 = s_nlpT[2*1024 + ct*64 + cq];
        float a3 = s_nlpT[3*1024 + ct*64 + cq];
        float a4 = s_nlpT[4*1024 + ct*64 + cq];
        float a5 = s_nlpT[5*1024 + ct*64 + cq];
        float a6 = s_nlpT[6*1024 + ct*64 + cq];
        int kk = NM >> 6;
        if (lane == (NM & 63) && NM < 128) {
          if (kk == 0) {
            mcol[0]=jf; mx[0]=nx; my[0]=ny; mz[0]=nz; mprow[0]=nr; mv[0]=0.f;
            mn0[0]=a0;mn1[0]=a1;mn2[0]=a2;mn3[0]=a3;mn4[0]=a4;mn5[0]=a5;mn6[0]=a6;
          } else {
            mcol[1]=jf; mx[1]=nx; my[1]=ny; mz[1]=nz; mprow[1]=nr; mv[1]=0.f;
            mn0[1]=a0;mn1[1]=a1;mn2[1]=a2;mn3[1]=a3;mn4[1]=a4;mn5[1]=a5;mn6[1]=a6;
          }
        }
        NM++;
      }
      while (pred) {
        int s = pred - 1, so = s & 63, sk = s >> 6;
        int np = __builtin_amdgcn_readlane(sk ? wsl[1] : wsl[0], so);
        int nr2;
        if (np == 0) nr2 = rfree;
        else {
          int s2 = np - 1;
          nr2 = __builtin_amdgcn_readlane((s2 >> 6) ? mprow[1] : mprow[0], s2 & 63);
        }
        int sc = __builtin_amdgcn_readlane(sk ? mcol[1] : mcol[0], so);
        if (lane == so) { if (sk) mprow[1] = nr2; else mprow[0] = nr2; }
        if (lane == 0) s_p[sc] = nr2;
        pred = np;
      }
      __threadfence_block();

      ru0 = vu[lane + 1];
      if (r1ok) ru1 = vu[lane + 65];
      #pragma unroll
      for (int k = 0; k < 2; k++)
        if ((lane + (k << 6)) < NM) mpu[k] = vu[mprow[k]];

      // free-structure maintenance
      if (lane == (jf / CPL)) fmask &= ~(1u << (jf - (jf / CPL) * CPL));
      if (rf1c0 == jf) { rf1v0 = rf2v0; rf1c0 = rf2c0; rf2c0 = -1; rf2v0 = INFF; }
      else if (rf2c0 == jf) { rf2c0 = -1; rf2v0 = INFF; }
      if (rf1c1 == jf) { rf1v1 = rf2v1; rf1c1 = rf2c1; rf2c1 = -1; rf2v1 = INFF; }
      else if (rf2c1 == jf) { rf2c1 = -1; rf2v1 = INFF; }
      unsigned long long need0 = __ballot(rf1c0 < 0);
      unsigned long long need1 = __ballot(r1ok && (rf1c1 < 0));
      while (need0) {
        int rb = (int)__builtin_ctzll(need0); need0 &= need0 - 1;
        int lab = __builtin_amdgcn_readlane(rlab0, rb);
        float gx = readlane_f(rgx0, rb), gy = readlane_f(rgy0, rb), gz = readlane_f(rgz0, rb);
        float v1, v2; int cc1, cc2;
        top2row(lab, gx, gy, gz, v1, cc1, v2, cc2);
        if (lane == rb) { rf1v0=v1; rf1c0=cc1; rf2v0=v2; rf2c0=cc2; }
      }
      while (need1) {
        int rb = (int)__builtin_ctzll(need1); need1 &= need1 - 1;
        int lab = __builtin_amdgcn_readlane(rlab1, rb);
        float gx = readlane_f(rgx1, rb), gy = readlane_f(rgy1, rb), gz = readlane_f(rgz1, rb);
        float v1, v2; int cc1, cc2;
        top2row(lab, gx, gy, gz, v1, cc1, v2, cc2);
        if (lane == rb) { rf1v1=v1; rf1c1=cc1; rf2v1=v2; rf2c1=cc2; }
      }
    }
  }

  // ---- Phase E: matched loss ----
  float ce = 0.f, l1 = 0.f;
  if (lval) {
    #pragma unroll
    for (int t = 0; t < CPL; t++) {
      int c = lane * CPL + t;
      int pr = s_p[c];
      if (pr > 0) {
        int g = pr - 1;
        int lg = s_glab[g];
        ce += s_nlpT[lg*1024 + t*64 + lane];
        float s = 0.f;
        #pragma unroll
        for (int d7 = 0; d7 < 7; d7++) s += fabsf(s_pb[c*NC+d7] - s_gb[g*NC+d7]);
        l1 += s;
      }
    }
  }
  float tot = ce * (1.f / NG) + l1 * (1.f / (NG * 7.f));
  tot = wave_sum_b(tot);
  if (lane == 0) atomicAdd(out, tot * inv_B);
}

extern "C" void kernel_launch(void* const* d_in, const int* in_sizes, int n_in,
                              void* d_out, int out_size, void* d_ws, size_t ws_size,
                              hipStream_t stream) {
  const float* logits  = (const float*)d_in[0];
  const float* pboxes  = (const float*)d_in[1];
  const int*   glabels = (const int*)d_in[2];
  const float* gboxes  = (const float*)d_in[3];
  float* out = (float*)d_out;
  const int B = in_sizes[0] / (NQ * NC);   // 128

  hipMemsetAsync(out, 0, sizeof(float), stream);
  hungarian_fused_kernel<<<dim3(B), dim3(256), 0, stream>>>(
      logits, pboxes, glabels, gboxes, out, 1.0f / (float)B);
}